// Round 1
// 77.788 us; speedup vs baseline: 1.0101x; 1.0101x over previous
//
#include <hip/hip_runtime.h>

// SpikingLayer forward: first-spike times of a delayed-synapse LIF layer.
// B=128, I=512+1 bias, O=512, STEPS=200.
// R6 = R5 with the prep_wi prologue folded into snn_fwd:
//  - weights are loaded as float4 and converted to fixed-point
//    (__float2int_rn(w * 2^23)) at CONSUME time, per event. Identical
//    expression to prep_wi => identical ints => identical (order-independent)
//    integer bin sums. Deletes one serialized dispatch + the d_ws round trip;
//    kernel no longer touches d_ws at all.
//  - __launch_bounds__ 6 -> 4 waves/SIMD: LDS (54 KB) already caps occupancy
//    at 2 blocks/CU = 4 waves/SIMD; the tighter reg budget bought nothing.
//  - bin_of lower clamp dropped: times >= 0 and delays = |N| >= 0 => s >= 0.
// Everything else as R5: stride-65 charge (bank=(s+col)%32), depth-2 global
// load pipeline, exact f64-mul binning (bit-identical to f32 divide),
// int LDS atomics, exact sequential phase 2 on wave 0, early exit.

#define IN_F    512
#define OUT_F   512
#define BATCH   128
#define STEPS   200
#define RES_F   1e-4f
#define CSTRIDE 65                           // stride-65: bank=(s+col)%32
// double exp(-1e-4/5e-3) = exp(-0.02), rounded to f32 by the literal:
#define DECAY_F 0.98019867330675525f
// double (1.0 - exp(-0.02)), rounded to f32:
#define ONEMD_F 0.019801326693244747f
#define SIM_T_F 2e-2f
#define FPSCALE 8388608.0f                   // 2^23
#define INVSCALE 1.1920928955078125e-07f     // 2^-23, exact

// q = fl32(arr / 1e-4f) computed exactly: (double)arr*10000.0 is exact,
// double->float is RNE == the IEEE f32 division result, bit for bit.
// arr >= 0 always here (times >= 0, delays >= 0) so only the upper clamp.
__device__ __forceinline__ int bin_of(float arr) {
    float q = (float)((double)arr * 10000.0);
    int s = __float2int_rn(q);               // RNE == np.round half-to-even
    return s > STEPS - 1 ? STEPS - 1 : s;
}

__global__ __launch_bounds__(512, 4) void snn_fwd(
    const float* __restrict__ input_times,   // [B, IN_F]
    const float* __restrict__ weights,       // [IN_F+1, OUT_F] f32
    const float* __restrict__ delays,        // [IN_F+1, OUT_F]
    const float* __restrict__ thresholds,    // [OUT_F]
    float* __restrict__ out)                 // [B, OUT_F]
{
#pragma clang fp contract(off)
    __shared__ __align__(16) int chargeI[STEPS * CSTRIDE];   // 52000 B
    __shared__ float times_s[IN_F];

    const int tid  = threadIdx.x;
    const int wv   = tid >> 6;               // wave 0..7
    const int lane = tid & 63;
    const int b     = blockIdx.x >> 3;
    const int otile = blockIdx.x & 7;
    const int ob    = otile << 6;            // output-column base

    // zero charge bins (int4) + stage this batch's input times
    {
        int4 z = make_int4(0, 0, 0, 0);
        int4* c4 = (int4*)chargeI;
        #pragma unroll
        for (int k = tid; k < (STEPS * CSTRIDE) / 4; k += 512) c4[k] = z;
    }
    times_s[tid] = input_times[b * IN_F + tid];   // IN_F == blockDim == 512
    __syncthreads();

    // --- Phase 1: bin synapse charges ---
    // lane -> (row-offset sub, column-group cg): one 16B load covers
    // 4 rows x 64 cols per wave. Wave wv handles rows [64*wv, 64*wv+64).
    const int sub = lane >> 4;               // 0..3
    const int cg  = (lane & 15) << 2;        // 0,4,...,60
    const float4* __restrict__ Wp = (const float4*)weights;
    const float4* __restrict__ Dp = (const float4*)delays;
    const int r0   = wv << 6;                                // first row
    const int i0   = (r0 + sub) * (OUT_F / 4) + ((ob + cg) >> 2); // vec4 index
    const int gstr = 4 * (OUT_F / 4);                        // 4 rows of vec4s

    // bias row (i=512, spike time 0): wave 7, one column per lane
    if (wv == 7) {
        float dl = delays[IN_F * OUT_F + ob + lane];
        int   wt = __float2int_rn(weights[IN_F * OUT_F + ob + lane] * FPSCALE);
        atomicAdd(&chargeI[bin_of(dl) * CSTRIDE + lane], wt);
    }

    // static depth-2 ping-pong over 16 vec4-steps (fully unrolled)
    float4 wA = Wp[i0],            wB = Wp[i0 + gstr];
    float4 dA = Dp[i0],            dB = Dp[i0 + gstr];
    float  tA = times_s[r0 + sub];
    float  tB = times_s[r0 + 4 + sub];

    #pragma unroll
    for (int g = 0; g < 16; g += 2) {
        float4 wC = {}, wD = {};
        float4 dC = {}, dD = {};
        float  tC = 0.f, tD = 0.f;
        if (g + 2 < 16) {
            wC = Wp[i0 + (g + 2) * gstr]; dC = Dp[i0 + (g + 2) * gstr];
            tC = times_s[r0 + ((g + 2) << 2) + sub];
        }
        if (g + 3 < 16) {
            wD = Wp[i0 + (g + 3) * gstr]; dD = Dp[i0 + (g + 3) * gstr];
            tD = times_s[r0 + ((g + 3) << 2) + sub];
        }
        {   // consume step g
            const float* dv = (const float*)&dA;
            const float* wf = (const float*)&wA;
            #pragma unroll
            for (int k = 0; k < 4; ++k) {
                int s  = bin_of(tA + dv[k]);
                int wt = __float2int_rn(wf[k] * FPSCALE);
                atomicAdd(&chargeI[s * CSTRIDE + cg + k], wt);  // ds_add_u32
            }
        }
        {   // consume step g+1
            const float* dv = (const float*)&dB;
            const float* wf = (const float*)&wB;
            #pragma unroll
            for (int k = 0; k < 4; ++k) {
                int s  = bin_of(tB + dv[k]);
                int wt = __float2int_rn(wf[k] * FPSCALE);
                atomicAdd(&chargeI[s * CSTRIDE + cg + k], wt);
            }
        }
        wA = wC; dA = dC; tA = tC;
        wB = wD; dB = dD; tB = tD;
    }
    __syncthreads();

    // --- Phase 2 (wave 0 only): exact sequential leaky integration ---
    if (wv == 0) {
        const float thr = thresholds[ob + lane];
        float syn = 0.f, mem = 0.f, spike_t = SIM_T_F;
        bool spiked = false;
        for (int t0 = 0; t0 < STEPS; t0 += 4) {
            float c[4];
            #pragma unroll
            for (int j = 0; j < 4; ++j)               // batch the ds_reads
                c[j] = (float)chargeI[(t0 + j) * CSTRIDE + lane] * INVSCALE;
            #pragma unroll
            for (int j = 0; j < 4; ++j) {
                float syn_n = syn * DECAY_F + c[j];               // no fma
                float mem_n = mem * DECAY_F + ONEMD_F * syn_n;    // no fma
                if (!spiked && mem_n >= thr) {
                    float denom = mem_n - mem;
                    float safe  = fabsf(denom) > 1e-12f ? denom : 1e-12f;
                    float frac  = (thr - mem) / safe;
                    frac = frac < 0.f ? 0.f : (frac > 1.f ? 1.f : frac);
                    spike_t = ((float)(t0 + j) + frac) * RES_F;
                    spiked  = true;
                }
                syn = syn_n; mem = mem_n;
            }
            if (__all(spiked)) break;        // all 64 lanes latched
        }
        out[b * OUT_F + ob + lane] = spike_t;
    }
}

extern "C" void kernel_launch(void* const* d_in, const int* in_sizes, int n_in,
                              void* d_out, int out_size, void* d_ws, size_t ws_size,
                              hipStream_t stream) {
    const float* input_times = (const float*)d_in[0];   // [128, 512]
    const float* weights     = (const float*)d_in[1];   // [513, 512]
    const float* delays      = (const float*)d_in[2];   // [513, 512]
    const float* thresholds  = (const float*)d_in[3];   // [512]
    float* out = (float*)d_out;                         // [128, 512]
    (void)d_ws; (void)ws_size;                          // workspace unused now

    dim3 grid(BATCH * (OUT_F / 64));   // 1024 blocks x 512 threads (8 waves)
    snn_fwd<<<grid, 512, 0, stream>>>(input_times, weights, delays,
                                      thresholds, out);
}

// Round 2
// 76.262 us; speedup vs baseline: 1.0303x; 1.0200x over previous
//
#include <hip/hip_runtime.h>

// SpikingLayer forward: first-spike times of a delayed-synapse LIF layer.
// B=128, I=512+1 bias, O=512, STEPS=200.
// R7 = R6 restructured to 2 batches per block (batch-pairing):
//  - weights/delays are batch-independent: loading + fixed-point-converting
//    them once per PAIR of batches halves global traffic and cuts ~27% of
//    phase-1 VALU (shared wt convert + shared d load, two bins/atomics).
//  - column tile halved to 32 (CSTRIDE=33, bank=(s+col)%32 unchanged mod 32)
//    so LDS = 2*52800/2 + ... = 56.9 KB and occupancy stays 2 blocks/CU.
//  - phase 2: one wave covers both batches: lane -> (batch=lane>>5,
//    col=lane&31); the two LDS charge arrays alias banks 2-way (free).
//  - all integer bin sums order-independent => bit-identical to R6.
// Everything else as R6: exact f64-mul binning (== IEEE f32 divide),
// int LDS atomics (ds_add_u32), depth-2 global load pipeline, early exit.

#define IN_F    512
#define OUT_F   512
#define BATCH   128
#define STEPS   200
#define RES_F   1e-4f
#define CSTRIDE 33                           // 32 cols + 1: bank=(s+col)%32
// double exp(-1e-4/5e-3) = exp(-0.02), rounded to f32 by the literal:
#define DECAY_F 0.98019867330675525f
// double (1.0 - exp(-0.02)), rounded to f32:
#define ONEMD_F 0.019801326693244747f
#define SIM_T_F 2e-2f
#define FPSCALE 8388608.0f                   // 2^23
#define INVSCALE 1.1920928955078125e-07f     // 2^-23, exact

// q = fl32(arr / 1e-4f) computed exactly: (double)arr*10000.0 is exact,
// double->float is RNE == the IEEE f32 division result, bit for bit.
// arr >= 0 always here (times >= 0, delays >= 0) so only the upper clamp.
__device__ __forceinline__ int bin_of(float arr) {
    float q = (float)((double)arr * 10000.0);
    int s = __float2int_rn(q);               // RNE == np.round half-to-even
    return s > STEPS - 1 ? STEPS - 1 : s;
}

__global__ __launch_bounds__(512, 4) void snn_fwd(
    const float* __restrict__ input_times,   // [B, IN_F]
    const float* __restrict__ weights,       // [IN_F+1, OUT_F] f32
    const float* __restrict__ delays,        // [IN_F+1, OUT_F]
    const float* __restrict__ thresholds,    // [OUT_F]
    float* __restrict__ out)                 // [B, OUT_F]
{
#pragma clang fp contract(off)
    __shared__ __align__(16) int chargeI[2][STEPS * CSTRIDE];  // 52800 B
    __shared__ float times_s[2][IN_F];                         // 4096 B

    const int tid  = threadIdx.x;
    const int wv   = tid >> 6;               // wave 0..7
    const int lane = tid & 63;
    const int b0    = (blockIdx.x >> 4) << 1;    // even batch of the pair
    const int otile = blockIdx.x & 15;
    const int ob    = otile << 5;                // output-column base (32-wide)

    // zero charge bins (int4) + stage both batches' input times
    {
        int4 z = make_int4(0, 0, 0, 0);
        int4* c4 = (int4*)&chargeI[0][0];
        for (int k = tid; k < (2 * STEPS * CSTRIDE) / 4; k += 512) c4[k] = z;
    }
    times_s[0][tid] = input_times[b0 * IN_F + tid];       // IN_F == blockDim
    times_s[1][tid] = input_times[(b0 + 1) * IN_F + tid];
    __syncthreads();

    // --- Phase 1: bin synapse charges for both batches ---
    // lane -> (row-offset sub 0..7, column-group cgi 0..7): one 16B load
    // covers 8 rows x 32 cols per wave-step. Wave wv owns rows [64wv,64wv+64).
    const int sub = lane >> 3;               // 0..7
    const int cgi = lane & 7;                // float4 column group
    const int cg  = cgi << 2;                // 0,4,...,28
    const float4* __restrict__ Wp = (const float4*)weights;
    const float4* __restrict__ Dp = (const float4*)delays;
    const int r0   = wv << 6;                                 // first row
    const int i0   = (r0 + sub) * (OUT_F / 4) + (ob >> 2) + cgi;
    const int gstr = 8 * (OUT_F / 4);                         // 8 rows of vec4s

    // bias row (i=512, spike time 0): wave 7, lane -> (batch, col)
    if (wv == 7) {
        const int bt = lane >> 5, col = lane & 31;
        float dl = delays[IN_F * OUT_F + ob + col];
        int   wt = __float2int_rn(weights[IN_F * OUT_F + ob + col] * FPSCALE);
        atomicAdd(&chargeI[bt][bin_of(dl) * CSTRIDE + col], wt);
    }

    // static depth-2 ping-pong over 8 vec4-steps (fully unrolled)
    float4 wA = Wp[i0],            wB = Wp[i0 + gstr];
    float4 dA = Dp[i0],            dB = Dp[i0 + gstr];
    float  tA0 = times_s[0][r0 + sub],     tA1 = times_s[1][r0 + sub];
    float  tB0 = times_s[0][r0 + 8 + sub], tB1 = times_s[1][r0 + 8 + sub];

    #pragma unroll
    for (int g = 0; g < 8; g += 2) {
        float4 wC = {}, wD = {};
        float4 dC = {}, dD = {};
        float  tC0 = 0.f, tC1 = 0.f, tD0 = 0.f, tD1 = 0.f;
        if (g + 2 < 8) {
            wC = Wp[i0 + (g + 2) * gstr]; dC = Dp[i0 + (g + 2) * gstr];
            tC0 = times_s[0][r0 + ((g + 2) << 3) + sub];
            tC1 = times_s[1][r0 + ((g + 2) << 3) + sub];
        }
        if (g + 3 < 8) {
            wD = Wp[i0 + (g + 3) * gstr]; dD = Dp[i0 + (g + 3) * gstr];
            tD0 = times_s[0][r0 + ((g + 3) << 3) + sub];
            tD1 = times_s[1][r0 + ((g + 3) << 3) + sub];
        }
        {   // consume step g: 4 synapses x 2 batches, shared weight convert
            const float* dv = (const float*)&dA;
            const float* wf = (const float*)&wA;
            #pragma unroll
            for (int k = 0; k < 4; ++k) {
                int wt = __float2int_rn(wf[k] * FPSCALE);
                atomicAdd(&chargeI[0][bin_of(tA0 + dv[k]) * CSTRIDE + cg + k], wt);
                atomicAdd(&chargeI[1][bin_of(tA1 + dv[k]) * CSTRIDE + cg + k], wt);
            }
        }
        {   // consume step g+1
            const float* dv = (const float*)&dB;
            const float* wf = (const float*)&wB;
            #pragma unroll
            for (int k = 0; k < 4; ++k) {
                int wt = __float2int_rn(wf[k] * FPSCALE);
                atomicAdd(&chargeI[0][bin_of(tB0 + dv[k]) * CSTRIDE + cg + k], wt);
                atomicAdd(&chargeI[1][bin_of(tB1 + dv[k]) * CSTRIDE + cg + k], wt);
            }
        }
        wA = wC; dA = dC; tA0 = tC0; tA1 = tC1;
        wB = wD; dB = dD; tB0 = tD0; tB1 = tD1;
    }
    __syncthreads();

    // --- Phase 2 (wave 0): exact sequential leaky integration ---
    // lane -> (batch bt, column col); covers both batches in one wave.
    if (wv == 0) {
        const int bt = lane >> 5, col = lane & 31;
        const float thr = thresholds[ob + col];
        float syn = 0.f, mem = 0.f, spike_t = SIM_T_F;
        bool spiked = false;
        for (int t0 = 0; t0 < STEPS; t0 += 4) {
            float c[4];
            #pragma unroll
            for (int j = 0; j < 4; ++j)               // batch the ds_reads
                c[j] = (float)chargeI[bt][(t0 + j) * CSTRIDE + col] * INVSCALE;
            #pragma unroll
            for (int j = 0; j < 4; ++j) {
                float syn_n = syn * DECAY_F + c[j];               // no fma
                float mem_n = mem * DECAY_F + ONEMD_F * syn_n;    // no fma
                if (!spiked && mem_n >= thr) {
                    float denom = mem_n - mem;
                    float safe  = fabsf(denom) > 1e-12f ? denom : 1e-12f;
                    float frac  = (thr - mem) / safe;
                    frac = frac < 0.f ? 0.f : (frac > 1.f ? 1.f : frac);
                    spike_t = ((float)(t0 + j) + frac) * RES_F;
                    spiked  = true;
                }
                syn = syn_n; mem = mem_n;
            }
            if (__all(spiked)) break;        // all 64 lanes latched
        }
        out[(b0 + bt) * OUT_F + ob + col] = spike_t;
    }
}

extern "C" void kernel_launch(void* const* d_in, const int* in_sizes, int n_in,
                              void* d_out, int out_size, void* d_ws, size_t ws_size,
                              hipStream_t stream) {
    const float* input_times = (const float*)d_in[0];   // [128, 512]
    const float* weights     = (const float*)d_in[1];   // [513, 512]
    const float* delays      = (const float*)d_in[2];   // [513, 512]
    const float* thresholds  = (const float*)d_in[3];   // [512]
    float* out = (float*)d_out;                         // [128, 512]
    (void)d_ws; (void)ws_size;                          // workspace unused

    // 64 batch-pairs x 16 column-tiles = 1024 blocks x 512 threads (8 waves)
    dim3 grid((BATCH / 2) * (OUT_F / 32));
    snn_fwd<<<grid, 512, 0, stream>>>(input_times, weights, delays,
                                      thresholds, out);
}

// Round 4
// 75.264 us; speedup vs baseline: 1.0440x; 1.0133x over previous
//
#include <hip/hip_runtime.h>

// SpikingLayer forward: first-spike times of a delayed-synapse LIF layer.
// B=128, I=512+1 bias, O=512, STEPS=200.
// R9 = R8 resubmitted verbatim (round-3 bench died on container acquisition,
// not the kernel: all loops compile-time bounded, addresses audited in-range,
// LDS 31.3KB, no workspace/host-API use).
// R8 rationale: R7 post-mortem: 2x load-sharing gained only 1.5us => phase 1
// is NOT load/VALU-throughput-bound. Utilization arithmetic (33.6M events /
// ~34us = 1.6 ev/cyc/CU, ~10% of VALU and DS capacity) says the kernel is
// latency-bound at 4 waves/SIMD (2 blocks/CU, LDS-capped). Changes:
//  - column tile 32 -> 16 (CSTRIDE 17, odd => bins still uniform mod 32
//    banks): LDS = 27.2KB charge + 4KB times = 31.3KB => 4 blocks/CU
//    = 32 waves/CU = 8 waves/SIMD (hardware max occupancy).
//  - __launch_bounds__(512, 8); per-wave state slimmed to fit 64 VGPR:
//    depth-1 prefetch ping-pong (cross-wave TLP now hides latency; the
//    deep pipeline was compensating for low occupancy).
//  - phase 2: 32 (batch,col) pairs; lanes 32-63 mirror 0-31 (harmless
//    duplicate compute, store guarded) so __all() early-exit still works.
//  - DS-atomic count and all arithmetic unchanged => bit-identical output.

#define IN_F    512
#define OUT_F   512
#define BATCH   128
#define STEPS   200
#define RES_F   1e-4f
#define COLS    16
#define CSTRIDE 17                           // 16 cols + 1; odd => banks spread
// double exp(-1e-4/5e-3) = exp(-0.02), rounded to f32 by the literal:
#define DECAY_F 0.98019867330675525f
// double (1.0 - exp(-0.02)), rounded to f32:
#define ONEMD_F 0.019801326693244747f
#define SIM_T_F 2e-2f
#define FPSCALE 8388608.0f                   // 2^23
#define INVSCALE 1.1920928955078125e-07f     // 2^-23, exact

// q = fl32(arr / 1e-4f) computed exactly: (double)arr*10000.0 is exact,
// double->float is RNE == the IEEE f32 division result, bit for bit.
// arr >= 0 always here (times >= 0, delays >= 0) so only the upper clamp.
__device__ __forceinline__ int bin_of(float arr) {
    float q = (float)((double)arr * 10000.0);
    int s = __float2int_rn(q);               // RNE == np.round half-to-even
    return s > STEPS - 1 ? STEPS - 1 : s;
}

__global__ __launch_bounds__(512, 8) void snn_fwd(
    const float* __restrict__ input_times,   // [B, IN_F]
    const float* __restrict__ weights,       // [IN_F+1, OUT_F] f32
    const float* __restrict__ delays,        // [IN_F+1, OUT_F]
    const float* __restrict__ thresholds,    // [OUT_F]
    float* __restrict__ out)                 // [B, OUT_F]
{
#pragma clang fp contract(off)
    __shared__ __align__(16) int chargeI[2][STEPS * CSTRIDE];  // 27,200 B
    __shared__ float times_s[2][IN_F];                         //  4,096 B

    const int tid  = threadIdx.x;
    const int wv   = tid >> 6;               // wave 0..7
    const int lane = tid & 63;
    const int b0    = (blockIdx.x >> 5) << 1;    // even batch of the pair
    const int otile = blockIdx.x & 31;
    const int ob    = otile << 4;                // output-column base (16-wide)

    // zero charge bins (int4) + stage both batches' input times
    {
        int4 z = make_int4(0, 0, 0, 0);
        int4* c4 = (int4*)&chargeI[0][0];
        for (int k = tid; k < (2 * STEPS * CSTRIDE) / 4; k += 512) c4[k] = z;
    }
    times_s[0][tid] = input_times[b0 * IN_F + tid];       // IN_F == blockDim
    times_s[1][tid] = input_times[(b0 + 1) * IN_F + tid];
    __syncthreads();

    // --- Phase 1: bin synapse charges for both batches ---
    // lane -> (row-offset sub 0..15, column-group cgi 0..3): one 16B load
    // covers 16 rows x 16 cols per wave-step. Wave wv owns rows
    // [64*wv, 64*wv+64) in 4 steps of 16.
    const int sub = lane >> 2;               // 0..15
    const int cgi = lane & 3;                // float4 column group
    const int cg  = cgi << 2;                // 0,4,8,12
    const float4* __restrict__ Wp = (const float4*)weights;
    const float4* __restrict__ Dp = (const float4*)delays;
    const int r0   = wv << 6;                                 // first row
    const int i0   = (r0 + sub) * (OUT_F / 4) + (ob >> 2) + cgi;
    const int gstr = 16 * (OUT_F / 4);                        // 16 rows of vec4

    // bias row (i=512, spike time 0): wave 7, lanes 0-31 -> (batch, col)
    if (wv == 7 && lane < 32) {
        const int bt = lane >> 4, col = lane & 15;
        float dl = delays[IN_F * OUT_F + ob + col];
        int   wt = __float2int_rn(weights[IN_F * OUT_F + ob + col] * FPSCALE);
        atomicAdd(&chargeI[bt][bin_of(dl) * CSTRIDE + col], wt);
    }

    // depth-1 ping-pong over 4 vec4-steps (8 waves/SIMD hide the rest)
    float4 wA = Wp[i0], dA = Dp[i0];
    float  tA0 = times_s[0][r0 + sub], tA1 = times_s[1][r0 + sub];

    #pragma unroll
    for (int g = 0; g < 4; ++g) {
        float4 wB = {}, dB = {};
        float  tB0 = 0.f, tB1 = 0.f;
        if (g + 1 < 4) {
            wB = Wp[i0 + (g + 1) * gstr]; dB = Dp[i0 + (g + 1) * gstr];
            tB0 = times_s[0][r0 + ((g + 1) << 4) + sub];
            tB1 = times_s[1][r0 + ((g + 1) << 4) + sub];
        }
        {   // consume step g: 4 synapses x 2 batches, shared weight convert
            const float* dv = (const float*)&dA;
            const float* wf = (const float*)&wA;
            #pragma unroll
            for (int k = 0; k < 4; ++k) {
                int wt = __float2int_rn(wf[k] * FPSCALE);
                atomicAdd(&chargeI[0][bin_of(tA0 + dv[k]) * CSTRIDE + cg + k], wt);
                atomicAdd(&chargeI[1][bin_of(tA1 + dv[k]) * CSTRIDE + cg + k], wt);
            }
        }
        wA = wB; dA = dB; tA0 = tB0; tA1 = tB1;
    }
    __syncthreads();

    // --- Phase 2 (wave 0): exact sequential leaky integration ---
    // 32 (batch,col) pairs; lanes 32-63 mirror lanes 0-31 so the
    // __all(spiked) early-exit sees a consistent full-wave predicate.
    if (wv == 0) {
        const int bt  = (lane >> 4) & 1;
        const int col = lane & 15;
        const float thr = thresholds[ob + col];
        float syn = 0.f, mem = 0.f, spike_t = SIM_T_F;
        bool spiked = false;
        for (int t0 = 0; t0 < STEPS; t0 += 4) {
            float c[4];
            #pragma unroll
            for (int j = 0; j < 4; ++j)               // batch the ds_reads
                c[j] = (float)chargeI[bt][(t0 + j) * CSTRIDE + col] * INVSCALE;
            #pragma unroll
            for (int j = 0; j < 4; ++j) {
                float syn_n = syn * DECAY_F + c[j];               // no fma
                float mem_n = mem * DECAY_F + ONEMD_F * syn_n;    // no fma
                if (!spiked && mem_n >= thr) {
                    float denom = mem_n - mem;
                    float safe  = fabsf(denom) > 1e-12f ? denom : 1e-12f;
                    float frac  = (thr - mem) / safe;
                    frac = frac < 0.f ? 0.f : (frac > 1.f ? 1.f : frac);
                    spike_t = ((float)(t0 + j) + frac) * RES_F;
                    spiked  = true;
                }
                syn = syn_n; mem = mem_n;
            }
            if (__all(spiked)) break;        // all lanes latched (mirrored)
        }
        if (lane < 32)
            out[(b0 + bt) * OUT_F + ob + col] = spike_t;
    }
}

extern "C" void kernel_launch(void* const* d_in, const int* in_sizes, int n_in,
                              void* d_out, int out_size, void* d_ws, size_t ws_size,
                              hipStream_t stream) {
    const float* input_times = (const float*)d_in[0];   // [128, 512]
    const float* weights     = (const float*)d_in[1];   // [513, 512]
    const float* delays      = (const float*)d_in[2];   // [513, 512]
    const float* thresholds  = (const float*)d_in[3];   // [512]
    float* out = (float*)d_out;                         // [128, 512]
    (void)d_ws; (void)ws_size;                          // workspace unused

    // 64 batch-pairs x 32 column-tiles = 2048 blocks x 512 threads (8 waves)
    dim3 grid((BATCH / 2) * (OUT_F / COLS));
    snn_fwd<<<grid, 512, 0, stream>>>(input_times, weights, delays,
                                      thresholds, out);
}